// Round 1
// baseline (144.706 us; speedup 1.0000x reference)
//
#include <hip/hip_runtime.h>
#include <stdint.h>

#define BB 16
#define NN 2048
#define DD 64
#define BM 128
#define BN 32
#define NWAVES 8
#define KSTR 72   // K_lds row stride in bf16 elems (144 B: 16B-aligned, 2-way banks)
#define VSTR 40   // Vt_lds row stride (80 B)
#define PSTR 40   // P_lds row stride (80 B)

typedef __attribute__((ext_vector_type(8))) short short8;
typedef __attribute__((ext_vector_type(4))) float f32x4;

__device__ __forceinline__ unsigned short f2bf(float f) {
  union { float f; uint32_t u; } c; c.f = f;
  uint32_t u = c.u + 0x7fffu + ((c.u >> 16) & 1u);  // RNE
  return (unsigned short)(u >> 16);
}

// ---- pre-pass 1: K fp32 -> bf16, straight copy (coalesced) ----
__global__ void cvt_k_kernel(const float* __restrict__ k, unsigned short* __restrict__ kbf) {
  int i = blockIdx.x * 256 + threadIdx.x;  // one float4 per thread; grid covers B*N*D/4
  float4 f = ((const float4*)k)[i];
  ushort4 o;
  o.x = f2bf(f.x); o.y = f2bf(f.y); o.z = f2bf(f.z); o.w = f2bf(f.w);
  ((ushort4*)kbf)[i] = o;
}

// ---- pre-pass 2: V fp32 [b][key][d] -> bf16 transposed vt [b][d][key] ----
__global__ __launch_bounds__(256) void tr_v_kernel(const float* __restrict__ v,
                                                   unsigned short* __restrict__ vt) {
  __shared__ float t[64][65];
  int b = blockIdx.x >> 5;           // 32 tiles of 64 keys per batch
  int k0 = (blockIdx.x & 31) * 64;
  const float4* src = (const float4*)(v + ((size_t)b * NN + k0) * DD);
  int tid = threadIdx.x;
#pragma unroll
  for (int i = 0; i < 4; i++) {
    int f4 = tid + i * 256;          // 0..1023 float4s of the 64x64 tile
    int row = f4 >> 4, c4 = f4 & 15;
    float4 f = src[f4];
    t[row][c4*4+0] = f.x; t[row][c4*4+1] = f.y; t[row][c4*4+2] = f.z; t[row][c4*4+3] = f.w;
  }
  __syncthreads();
  int d = tid >> 2, kg = tid & 3;    // each thread writes 16 keys of row d
  unsigned short* dst = vt + ((size_t)b * DD + d) * NN + k0 + kg * 16;
#pragma unroll
  for (int u = 0; u < 4; u++) {
    ushort4 o;
    o.x = f2bf(t[kg*16+u*4+0][d]);
    o.y = f2bf(t[kg*16+u*4+1][d]);
    o.z = f2bf(t[kg*16+u*4+2][d]);
    o.w = f2bf(t[kg*16+u*4+3][d]);
    ((ushort4*)dst)[u] = o;
  }
}

// ---- main flash-attention kernel ----
__global__ __launch_bounds__(512, 1) void attn_kernel(
    const float* __restrict__ q, const unsigned short* __restrict__ kbf,
    const unsigned short* __restrict__ vtbf, const int* __restrict__ valid,
    float* __restrict__ out)
{
  __shared__ __align__(16) unsigned short Klds[32 * KSTR];
  __shared__ __align__(16) unsigned short Vlds[64 * VSTR];
  __shared__ __align__(16) unsigned short Plds[NWAVES * 16 * PSTR];
  __shared__ int vld[BM];

  // XCD swizzle: blocks with id%8==x land on XCD x (typical RR dispatch);
  // give each XCD 2 batches so K+V bf16 (1 MB) stays L2-resident.
  int id = blockIdx.x;
  int x = id & 7, r = id >> 3;       // r in 0..31
  int b = x + 8 * (r >> 4);          // batch 0..15
  int i0 = (r & 15) * BM;            // query-tile base

  int tid = threadIdx.x;
  int w = tid >> 6;                  // wave 0..7, owns queries i0+w*16 .. +15
  int lane = tid & 63;
  int m = lane & 15;
  int quad = lane >> 4;

  if (tid < BM) vld[tid] = valid[b * NN + i0 + tid];

  // Q fragments (A layout: A[m=lane&15][k=quad*8+j]), fp32 -> bf16 on the fly
  short8 qf[2];
  {
    const float* qp = q + ((size_t)b * NN + (i0 + w * 16 + m)) * DD;
#pragma unroll
    for (int s = 0; s < 2; s++) {
      float4 f0 = *(const float4*)(qp + s * 32 + quad * 8);
      float4 f1 = *(const float4*)(qp + s * 32 + quad * 8 + 4);
      union { short8 v; unsigned short u[8]; } tmp;
      tmp.u[0]=f2bf(f0.x); tmp.u[1]=f2bf(f0.y); tmp.u[2]=f2bf(f0.z); tmp.u[3]=f2bf(f0.w);
      tmp.u[4]=f2bf(f1.x); tmp.u[5]=f2bf(f1.y); tmp.u[6]=f2bf(f1.z); tmp.u[7]=f2bf(f1.w);
      qf[s] = tmp.v;
    }
  }

  __syncthreads();
  int vr[4];
#pragma unroll
  for (int rr = 0; rr < 4; rr++) vr[rr] = vld[w * 16 + quad * 4 + rr];

  const float CM = __expf(1.0e-6f);  // masked-position weight (NOT zero!)
  f32x4 o[4] = {{0,0,0,0},{0,0,0,0},{0,0,0,0},{0,0,0,0}};
  float z[4] = {0,0,0,0};

  unsigned short* pbase = Plds + w * 16 * PSTR;

  for (int j0 = 0; j0 < NN; j0 += BN) {
    __syncthreads();  // prior tile fully consumed
    {
      int key = tid >> 4, part = tid & 15;   // K tile: 32 keys x 64 d
      *(ushort4*)&Klds[key * KSTR + part * 4] =
          *(const ushort4*)(kbf + ((size_t)b * NN + j0 + key) * DD + part * 4);
      int d = tid >> 3, p2 = tid & 7;        // Vt tile: 64 d x 32 keys
      *(ushort4*)&Vlds[d * VSTR + p2 * 4] =
          *(const ushort4*)(vtbf + ((size_t)b * DD + d) * NN + j0 + p2 * 4);
    }
    __syncthreads();

    // S = Q . K^T : two 16x16 key subtiles, two K-steps of 32 over d=64
    f32x4 s0 = {0,0,0,0}, s1 = {0,0,0,0};
#pragma unroll
    for (int s = 0; s < 2; s++) {
      short8 kf0 = *(const short8*)&Klds[m * KSTR + s * 32 + quad * 8];
      short8 kf1 = *(const short8*)&Klds[(16 + m) * KSTR + s * 32 + quad * 8];
      s0 = __builtin_amdgcn_mfma_f32_16x16x32_bf16(qf[s], kf0, s0, 0, 0, 0);
      s1 = __builtin_amdgcn_mfma_f32_16x16x32_bf16(qf[s], kf1, s1, 0, 0, 0);
    }

    // P = exp(s/8) for j < valid, else exp(1e-6); accumulate row-sums
#pragma unroll
    for (int rr = 0; rr < 4; rr++) {
      float e0 = (j0 + m < vr[rr])      ? __expf(s0[rr] * 0.125f) : CM;
      float e1 = (j0 + 16 + m < vr[rr]) ? __expf(s1[rr] * 0.125f) : CM;
      z[rr] += e0 + e1;
      int qrow = quad * 4 + rr;           // C layout: row=quad*4+reg, col=m
      pbase[qrow * PSTR + m]      = f2bf(e0);
      pbase[qrow * PSTR + 16 + m] = f2bf(e1);
    }

    // wave-local LDS RAW: DS ops are in-order per wave; drain write data
    __builtin_amdgcn_s_waitcnt(0xc07f);  // lgkmcnt(0) only

    // P back in A layout; O += P . V  (4 d-subtiles of 16)
    short8 pf = *(const short8*)&pbase[m * PSTR + quad * 8];
#pragma unroll
    for (int t = 0; t < 4; t++) {
      short8 vf = *(const short8*)&Vlds[(t * 16 + m) * VSTR + quad * 8];
      o[t] = __builtin_amdgcn_mfma_f32_16x16x32_bf16(pf, vf, o[t], 0, 0, 0);
    }
  }

  // reduce z across the 16 lanes holding the same rows (cols 0..15)
#pragma unroll
  for (int rr = 0; rr < 4; rr++) {
    float zz = z[rr];
    zz += __shfl_xor(zz, 1, 16);
    zz += __shfl_xor(zz, 2, 16);
    zz += __shfl_xor(zz, 4, 16);
    zz += __shfl_xor(zz, 8, 16);
    z[rr] = 1.0f / zz;
  }

#pragma unroll
  for (int rr = 0; rr < 4; rr++) {
    int row = i0 + w * 16 + quad * 4 + rr;
    float* op = out + ((size_t)b * NN + row) * DD + m;
#pragma unroll
    for (int t = 0; t < 4; t++) op[t * 16] = o[t][rr] * z[rr];
  }
}

extern "C" void kernel_launch(void* const* d_in, const int* in_sizes, int n_in,
                              void* d_out, int out_size, void* d_ws, size_t ws_size,
                              hipStream_t stream) {
  const float* q = (const float*)d_in[0];
  const float* k = (const float*)d_in[1];
  const float* v = (const float*)d_in[2];
  const int* valid = (const int*)d_in[3];
  float* out = (float*)d_out;

  unsigned short* kbf  = (unsigned short*)d_ws;                 // 4 MB
  unsigned short* vtbf = kbf + (size_t)BB * NN * DD;            // 4 MB

  hipLaunchKernelGGL(cvt_k_kernel, dim3((BB * NN * DD / 4) / 256), dim3(256), 0, stream, k, kbf);
  hipLaunchKernelGGL(tr_v_kernel, dim3(BB * (NN / 64)), dim3(256), 0, stream, v, vtbf);
  hipLaunchKernelGGL(attn_kernel, dim3(BB * (NN / BM)), dim3(512), 0, stream,
                     q, kbf, vtbf, valid, out);
}

// Round 2
// 117.221 us; speedup vs baseline: 1.2345x; 1.2345x over previous
//
#include <hip/hip_runtime.h>
#include <stdint.h>

#define BB 16
#define NN 2048
#define DD 64
#define BM 64
#define BN 64
#define KSTR 72   // K/Vt LDS row stride in bf16 elems (144 B: 16B-aligned, 2-way banks free)
#define PSTR 72   // P LDS row stride

typedef __attribute__((ext_vector_type(8))) short short8;
typedef __attribute__((ext_vector_type(4))) float f32x4;

__device__ __forceinline__ unsigned short f2bf(float f) {   // RNE (pre-pass)
  union { float f; uint32_t u; } c; c.f = f;
  uint32_t u = c.u + 0x7fffu + ((c.u >> 16) & 1u);
  return (unsigned short)(u >> 16);
}
__device__ __forceinline__ unsigned short f2bf_fast(float f) {  // round-half-up (hot loop)
  union { float f; uint32_t u; } c; c.f = f;
  return (unsigned short)((c.u + 0x8000u) >> 16);
}

// ---- fused pre-pass: blocks [0,2048): K fp32->bf16 copy; [2048,2560): V transpose ----
__global__ __launch_bounds__(256) void prep_kernel(const float* __restrict__ k,
                                                   const float* __restrict__ v,
                                                   unsigned short* __restrict__ kbf,
                                                   unsigned short* __restrict__ vt) {
  __shared__ float t[64][65];
  int id = blockIdx.x, tid = threadIdx.x;
  if (id < 2048) {
    int i = id * 256 + tid;
    float4 f = ((const float4*)k)[i];
    ushort4 o;
    o.x = f2bf(f.x); o.y = f2bf(f.y); o.z = f2bf(f.z); o.w = f2bf(f.w);
    ((ushort4*)kbf)[i] = o;
  } else {
    int bid = id - 2048;
    int b = bid >> 5;
    int k0 = (bid & 31) * 64;
    const float4* src = (const float4*)(v + ((size_t)b * NN + k0) * DD);
#pragma unroll
    for (int i = 0; i < 4; i++) {
      int f4 = tid + i * 256;
      int row = f4 >> 4, c4 = f4 & 15;
      float4 f = src[f4];
      t[row][c4*4+0] = f.x; t[row][c4*4+1] = f.y; t[row][c4*4+2] = f.z; t[row][c4*4+3] = f.w;
    }
    __syncthreads();
    int d = tid >> 2, kg = tid & 3;
    unsigned short* dst = vt + ((size_t)b * DD + d) * NN + k0 + kg * 16;
#pragma unroll
    for (int u = 0; u < 4; u++) {
      ushort4 o;
      o.x = f2bf(t[kg*16+u*4+0][d]);
      o.y = f2bf(t[kg*16+u*4+1][d]);
      o.z = f2bf(t[kg*16+u*4+2][d]);
      o.w = f2bf(t[kg*16+u*4+3][d]);
      ((ushort4*)dst)[u] = o;
    }
  }
}

// ---- main flash-attention kernel, optional split-K ----
__global__ __launch_bounds__(256, 4) void attn_kernel(
    const float* __restrict__ q, const unsigned short* __restrict__ kbf,
    const unsigned short* __restrict__ vtbf, const int* __restrict__ valid,
    float* __restrict__ out, unsigned short* __restrict__ po,
    float* __restrict__ pz, int nsplit)
{
  __shared__ __align__(16) unsigned short Klds[BN * KSTR];
  __shared__ __align__(16) unsigned short Vlds[DD * KSTR];
  __shared__ __align__(16) unsigned short Plds[4 * 16 * PSTR];
  __shared__ int vld[BM];

  // decode with XCD swizzle: id&7 = XCD; 2 batches per XCD for L2 K/V residency
  int id = blockIdx.x;
  int x = id & 7, r = id >> 3;
  int b = x + 8 * (r & 1);
  int r2 = r >> 1;
  int sp, qt;
  if (nsplit == 2) { sp = r2 & 1; qt = r2 >> 1; }
  else             { sp = 0;      qt = r2;      }
  int i0 = qt * BM;
  int jbase = sp * (NN / nsplit);
  int jlen  = NN / nsplit;

  int tid = threadIdx.x;
  int w = tid >> 6;            // wave 0..3, owns queries i0 + w*16 .. +15
  int lane = tid & 63;
  int m = lane & 15;
  int quad = lane >> 4;

  if (tid < BM) vld[tid] = valid[b * NN + i0 + tid];

  // Q fragments (A layout), scale 1/sqrt(64)=0.125 folded in, fp32->bf16
  short8 qf[2];
  {
    const float* qp = q + ((size_t)b * NN + (i0 + w * 16 + m)) * DD;
#pragma unroll
    for (int s = 0; s < 2; s++) {
      float4 f0 = *(const float4*)(qp + s * 32 + quad * 8);
      float4 f1 = *(const float4*)(qp + s * 32 + quad * 8 + 4);
      union { short8 v; unsigned short u[8]; } tmp;
      tmp.u[0]=f2bf(f0.x*0.125f); tmp.u[1]=f2bf(f0.y*0.125f);
      tmp.u[2]=f2bf(f0.z*0.125f); tmp.u[3]=f2bf(f0.w*0.125f);
      tmp.u[4]=f2bf(f1.x*0.125f); tmp.u[5]=f2bf(f1.y*0.125f);
      tmp.u[6]=f2bf(f1.z*0.125f); tmp.u[7]=f2bf(f1.w*0.125f);
      qf[s] = tmp.v;
    }
  }

  __syncthreads();
  int vr[4];
#pragma unroll
  for (int rr = 0; rr < 4; rr++) vr[rr] = vld[w * 16 + quad * 4 + rr];

  f32x4 o[4] = {{0,0,0,0},{0,0,0,0},{0,0,0,0},{0,0,0,0}};
  float z[4] = {0,0,0,0};
  unsigned short* pbase = Plds + w * 16 * PSTR;

  // staging indices: thread t loads 16 contiguous elems of row t>>2 at col (t&3)*16
  int srow = tid >> 2, scol = (tid & 3) * 16;
  const unsigned short* gk = kbf + ((size_t)(b * NN + jbase + srow)) * DD + scol;
  const unsigned short* gv = vtbf + ((size_t)b * DD + srow) * NN + jbase + scol;

  uint4 ka = *(const uint4*)gk, kb2 = *(const uint4*)(gk + 8);
  uint4 va = *(const uint4*)gv, vb2 = *(const uint4*)(gv + 8);

  int iters = jlen / BN;
  for (int it = 0; it < iters; ++it) {
    int j0 = jbase + it * BN;
    __syncthreads();   // prior tile consumed
    *(uint4*)&Klds[srow * KSTR + scol]     = ka;
    *(uint4*)&Klds[srow * KSTR + scol + 8] = kb2;
    *(uint4*)&Vlds[srow * KSTR + scol]     = va;
    *(uint4*)&Vlds[srow * KSTR + scol + 8] = vb2;
    if (it + 1 < iters) {   // prefetch next tile; latency overlaps compute below
      gk += BN * DD; gv += BN;
      ka = *(const uint4*)gk; kb2 = *(const uint4*)(gk + 8);
      va = *(const uint4*)gv; vb2 = *(const uint4*)(gv + 8);
    }
    __syncthreads();

    // S = Q.K^T : 4 key-subtiles x 2 d-steps
    f32x4 s[4] = {{0,0,0,0},{0,0,0,0},{0,0,0,0},{0,0,0,0}};
#pragma unroll
    for (int sub = 0; sub < 4; sub++) {
#pragma unroll
      for (int ss = 0; ss < 2; ss++) {
        short8 kf = *(const short8*)&Klds[(sub * 16 + m) * KSTR + ss * 32 + quad * 8];
        s[sub] = __builtin_amdgcn_mfma_f32_16x16x32_bf16(qf[ss], kf, s[sub], 0, 0, 0);
      }
    }

    // P = exp(score) with masked-score = 1e-6 (weight ~1, NOT zero)
#pragma unroll
    for (int sub = 0; sub < 4; sub++) {
      int j = j0 + sub * 16 + m;
#pragma unroll
      for (int rr = 0; rr < 4; rr++) {
        float arg = (j < vr[rr]) ? s[sub][rr] : 1.0e-6f;
        float e = __expf(arg);
        z[rr] += e;
        pbase[(quad * 4 + rr) * PSTR + sub * 16 + m] = f2bf_fast(e);
      }
    }

    __builtin_amdgcn_s_waitcnt(0xc07f);  // lgkmcnt(0): wave-local P RAW

    // O += P.V
#pragma unroll
    for (int ss = 0; ss < 2; ss++) {
      short8 pf = *(const short8*)&pbase[m * PSTR + ss * 32 + quad * 8];
#pragma unroll
      for (int t = 0; t < 4; t++) {
        short8 vf = *(const short8*)&Vlds[(t * 16 + m) * KSTR + ss * 32 + quad * 8];
        o[t] = __builtin_amdgcn_mfma_f32_16x16x32_bf16(pf, vf, o[t], 0, 0, 0);
      }
    }
  }

  // reduce z across the 16 key-lanes
  float zred[4];
#pragma unroll
  for (int rr = 0; rr < 4; rr++) {
    float zz = z[rr];
    zz += __shfl_xor(zz, 1, 16);
    zz += __shfl_xor(zz, 2, 16);
    zz += __shfl_xor(zz, 4, 16);
    zz += __shfl_xor(zz, 8, 16);
    zred[rr] = zz;
  }

  if (nsplit == 2) {
#pragma unroll
    for (int rr = 0; rr < 4; rr++) {
      int row = i0 + w * 16 + quad * 4 + rr;
      unsigned short* op = po + ((size_t)((sp * BB + b) * NN) + row) * DD + m;
#pragma unroll
      for (int t = 0; t < 4; t++) op[t * 16] = f2bf_fast(o[t][rr]);
      if (m == 0) pz[(size_t)(sp * BB + b) * NN + row] = zred[rr];
    }
  } else {
#pragma unroll
    for (int rr = 0; rr < 4; rr++) {
      float inv = 1.0f / zred[rr];
      int row = i0 + w * 16 + quad * 4 + rr;
      float* op = out + ((size_t)b * NN + row) * DD + m;
#pragma unroll
      for (int t = 0; t < 4; t++) op[t * 16] = o[t][rr] * inv;
    }
  }
}

// ---- combine: out = (po0+po1)/(z0+z1) ----
__global__ __launch_bounds__(256) void combine_kernel(const unsigned short* __restrict__ po,
                                                      const float* __restrict__ pz,
                                                      float* __restrict__ out) {
  int gid = blockIdx.x * 256 + threadIdx.x;   // 262144 threads, 8 elems each
  size_t base = (size_t)gid * 8;
  int rowz = gid >> 3;
  uint4 a = *(const uint4*)(po + base);
  uint4 c = *(const uint4*)(po + (size_t)BB * NN * DD + base);
  float inv = 1.0f / (pz[rowz] + pz[(size_t)BB * NN + rowz]);
  uint32_t aw[4] = {a.x, a.y, a.z, a.w}, cw[4] = {c.x, c.y, c.z, c.w};
  float r[8];
#pragma unroll
  for (int i = 0; i < 4; i++) {
    float alo = __uint_as_float(aw[i] << 16), ahi = __uint_as_float(aw[i] & 0xffff0000u);
    float clo = __uint_as_float(cw[i] << 16), chi = __uint_as_float(cw[i] & 0xffff0000u);
    r[2*i]   = (alo + clo) * inv;
    r[2*i+1] = (ahi + chi) * inv;
  }
  float4* op = (float4*)(out + base);
  op[0] = make_float4(r[0], r[1], r[2], r[3]);
  op[1] = make_float4(r[4], r[5], r[6], r[7]);
}

extern "C" void kernel_launch(void* const* d_in, const int* in_sizes, int n_in,
                              void* d_out, int out_size, void* d_ws, size_t ws_size,
                              hipStream_t stream) {
  const float* q = (const float*)d_in[0];
  const float* k = (const float*)d_in[1];
  const float* v = (const float*)d_in[2];
  const int* valid = (const int*)d_in[3];
  float* out = (float*)d_out;

  unsigned short* kbf  = (unsigned short*)d_ws;                    // 4 MB
  unsigned short* vtbf = kbf + (size_t)BB * NN * DD;               // 4 MB
  unsigned short* po   = vtbf + (size_t)BB * NN * DD;              // 2 x 4 MB bf16 partial O
  float* pz = (float*)(po + (size_t)2 * BB * NN * DD);             // 2 x 128 KB partial z

  size_t need = (size_t)4 * BB * NN * DD * 2 + (size_t)2 * BB * NN * 4;
  int nsplit = (ws_size >= need) ? 2 : 1;

  hipLaunchKernelGGL(prep_kernel, dim3(2560), dim3(256), 0, stream, k, v, kbf, vtbf);
  hipLaunchKernelGGL(attn_kernel, dim3(512 * nsplit), dim3(256), 0, stream,
                     q, kbf, vtbf, valid, out, po, pz, nsplit);
  if (nsplit == 2)
    hipLaunchKernelGGL(combine_kernel, dim3(1024), dim3(256), 0, stream, po, pz, out);
}